// Round 2
// baseline (488.554 us; speedup 1.0000x reference)
//
#include <hip/hip_runtime.h>

#define HH 512
#define WW 512
#define HW 262144          // 512*512
#define NPIX 1048576       // 4*512*512
#define NPIXF 1048576.0f

typedef float f4 __attribute__((ext_vector_type(4)));

__device__ __forceinline__ float leaky(float v) { return v > 0.f ? v : 0.01f * v; }

// replication count of source index i at level size s (nearest upsample to 512)
__device__ __forceinline__ float repw(int i, int s) {
    return (float)(((i + 1) * 512 + s - 1) / s - (i * 512 + s - 1) / s);
}

__device__ __forceinline__ void hins(unsigned long long& h0, unsigned long long& h1,
                                     unsigned& c16, int val) {
    unsigned long long inc = 1ull << ((val & 7) * 8);
    h0 += (val < 8) ? inc : 0;
    h1 += (val >= 8 && val < 16) ? inc : 0;
    c16 += (unsigned)(val >> 4);
}
__device__ __forceinline__ void hrem(unsigned long long& h0, unsigned long long& h1,
                                     unsigned& c16, int val) {
    unsigned long long inc = 1ull << ((val & 7) * 8);
    h0 -= (val < 8) ? inc : 0;
    h1 -= (val >= 8 && val < 16) ? inc : 0;
    c16 -= (unsigned)(val >> 4);
}

// Load the 11-byte window [t, t+10] of staged row rr as three u32 (w0=bytes0-3,
// w1=bytes4-7, w2=bytes8-10). Base is 4-aligned; row stride 272 is 16-aligned.
__device__ __forceinline__ void win3(const unsigned char* q, int rr, int t,
                                     unsigned& w0, unsigned& w1, unsigned& w2) {
    const unsigned* p = (const unsigned*)(q + rr * 272 + (t & ~3));
    unsigned a0 = p[0], a1 = p[1], a2 = p[2], a3 = p[3];
    int sh = (t & 3) * 8;
    unsigned long long u01 = ((unsigned long long)a1 << 32) | a0;
    unsigned long long u12 = ((unsigned long long)a2 << 32) | a1;
    unsigned long long u23 = ((unsigned long long)a3 << 32) | a2;
    w0 = (unsigned)(u01 >> sh);
    w1 = (unsigned)(u12 >> sh);
    w2 = (unsigned)(u23 >> sh);
}

__device__ __forceinline__ void winadd(const unsigned char* q, int rr, int t,
                                       unsigned long long& H0, unsigned long long& H1,
                                       unsigned& C) {
    unsigned w0, w1, w2;
    win3(q, rr, t, w0, w1, w2);
    #pragma unroll
    for (int i = 0; i < 4; ++i) hins(H0, H1, C, (w0 >> (8 * i)) & 0xFF);
    #pragma unroll
    for (int i = 0; i < 4; ++i) hins(H0, H1, C, (w1 >> (8 * i)) & 0xFF);
    #pragma unroll
    for (int i = 0; i < 3; ++i) hins(H0, H1, C, (w2 >> (8 * i)) & 0xFF);
}

__device__ __forceinline__ void winrem(const unsigned char* q, int rr, int t,
                                       unsigned long long& H0, unsigned long long& H1,
                                       unsigned& C) {
    unsigned w0, w1, w2;
    win3(q, rr, t, w0, w1, w2);
    #pragma unroll
    for (int i = 0; i < 4; ++i) hrem(H0, H1, C, (w0 >> (8 * i)) & 0xFF);
    #pragma unroll
    for (int i = 0; i < 4; ++i) hrem(H0, H1, C, (w1 >> (8 * i)) & 0xFF);
    #pragma unroll
    for (int i = 0; i < 3; ++i) hrem(H0, H1, C, (w2 >> (8 * i)) & 0xFF);
}

// ---------------------------------------------------------------------------
// Mode pooling v4: full 11x11 window histogram kept per-thread in registers
// (2xu64 byte-packed + u32), slid vertically one row at a time. LDS traffic
// in the main loop is 8 ds_read_b32 per row (was 55 reads + writes); no
// per-row barriers. Quantize + tie-break scan byte-identical to v3.
// ---------------------------------------------------------------------------
__global__ __launch_bounds__(256) void mode_kernel(const float* __restrict__ x,
                                                   unsigned char* __restrict__ modeq) {
    __shared__ unsigned char q[26 * 272];
    const int plane = blockIdx.z;
    const int tc0 = blockIdx.x * 256;
    const int tr0 = blockIdx.y * 16;
    const float* xp = x + (size_t)plane * HW;
    for (int idx = threadIdx.x; idx < 26 * 266; idx += 256) {
        int r = idx / 266;
        int cc = idx - r * 266;
        int gr = tr0 + r - 5; gr = gr < 0 ? -gr : (gr > 511 ? 1022 - gr : gr);
        int gc = tc0 + cc - 5; gc = gc < 0 ? -gc : (gc > 511 ? 1022 - gc : gc);
        float v = rintf(xp[gr * WW + gc] * 15.9375f);   // 255/16, round-half-even
        v = fminf(fmaxf(v, 0.f), 16.f);
        q[r * 272 + cc] = (unsigned char)(int)v;
    }
    __syncthreads();
    const int t = threadIdx.x;
    unsigned long long H0 = 0, H1 = 0; unsigned C = 0;
    #pragma unroll 1
    for (int rr = 0; rr < 11; ++rr) winadd(q, rr, t, H0, H1, C);
    #pragma unroll 1
    for (int r = 0; r < 16; ++r) {
        if (r > 0) {
            winrem(q, r - 1, t, H0, H1, C);
            winadd(q, r + 10, t, H0, H1, C);
        }
        unsigned m = 0;
        #pragma unroll
        for (int i = 0; i < 8; ++i) {
            unsigned cnt = (unsigned)(H0 >> (8 * i)) & 0xFFu;
            unsigned val = (cnt << 8) | (unsigned)(16 - i);
            m = m > val ? m : val;
        }
        #pragma unroll
        for (int i = 8; i < 16; ++i) {
            unsigned cnt = (unsigned)(H1 >> (8 * (i - 8))) & 0xFFu;
            unsigned val = (cnt << 8) | (unsigned)(16 - i);
            m = m > val ? m : val;
        }
        unsigned val16 = (C << 8);
        m = m > val16 ? m : val16;
        int k = 16 - (int)(m & 0xFFu);
        modeq[(size_t)plane * HW + (size_t)(tr0 + r) * WW + tc0 + t] = (unsigned char)k;
    }
}

// ---------------------------------------------------------------------------
// Joint histogram + per-block t1 moments. Now 256 blocks (full CU coverage,
// 4096 px each); partial is 256*4913, mpart 256*27.
// ---------------------------------------------------------------------------
__global__ __launch_bounds__(256) void hist_kernel(const unsigned char* __restrict__ modeq,
                                                   const float* __restrict__ w1,
                                                   const float* __restrict__ b1,
                                                   unsigned* __restrict__ partial,
                                                   float* __restrict__ mpart) {
    __shared__ unsigned lh[4913];
    __shared__ float mred[27][4];
    for (int i = threadIdx.x; i < 4913; i += 256) lh[i] = 0;
    __syncthreads();
    int base = blockIdx.x * 4096;
    int b = base >> 18;
    int hw0 = base & (HW - 1);
    const unsigned char* mp = modeq + (size_t)b * 3 * HW;
    #pragma unroll
    for (int j = 0; j < 4; ++j) {
        int g = threadIdx.x + 256 * j;
        int hw = hw0 + g * 4;
        unsigned u0 = *(const unsigned*)(mp + hw);
        unsigned u1 = *(const unsigned*)(mp + hw + HW);
        unsigned u2 = *(const unsigned*)(mp + hw + 2 * HW);
        #pragma unroll
        for (int k = 0; k < 4; ++k) {
            int k0 = (u0 >> (8 * k)) & 0xFF;
            int k1 = (u1 >> (8 * k)) & 0xFF;
            int k2 = (u2 >> (8 * k)) & 0xFF;
            atomicAdd(&lh[k0 + 17 * k1 + 289 * k2], 1u);
        }
    }
    __syncthreads();
    unsigned* pp = partial + blockIdx.x * 4913;
    for (int i = threadIdx.x; i < 4913; i += 256) pp[i] = lh[i];
    float w1r[18], b1r[6];
    #pragma unroll
    for (int k = 0; k < 18; ++k) w1r[k] = w1[k];
    #pragma unroll
    for (int o = 0; o < 6; ++o) b1r[o] = b1[o];
    float M[27];
    #pragma unroll
    for (int i = 0; i < 27; ++i) M[i] = 0.f;
    for (int bin = threadIdx.x; bin < 4913; bin += 256) {
        float cnt = (float)lh[bin];
        int k0 = bin % 17;
        int r = bin / 17;
        int k1 = r % 17;
        int k2 = r / 17;
        float xm0 = k0 * 0.0625f, xm1 = k1 * 0.0625f, xm2 = k2 * 0.0625f;
        float t1[6];
        #pragma unroll
        for (int o = 0; o < 6; ++o)
            t1[o] = leaky(xm0 * w1r[o * 3] + xm1 * w1r[o * 3 + 1] + xm2 * w1r[o * 3 + 2] + b1r[o]);
        #pragma unroll
        for (int o = 0; o < 6; ++o) M[o] += cnt * t1[o];
        int ii = 6;
        #pragma unroll
        for (int j = 0; j < 6; ++j)
            #pragma unroll
            for (int k = j; k < 6; ++k) { M[ii] += cnt * t1[j] * t1[k]; ++ii; }
    }
    int wv = threadIdx.x >> 6;
    #pragma unroll
    for (int i = 0; i < 27; ++i) {
        float v = M[i];
        #pragma unroll
        for (int off = 32; off >= 1; off >>= 1) v += __shfl_xor(v, off);
        if ((threadIdx.x & 63) == 0) mred[i][wv] = v;
    }
    __syncthreads();
    if (threadIdx.x < 27)
        mpart[blockIdx.x * 27 + threadIdx.x] =
            mred[threadIdx.x][0] + mred[threadIdx.x][1] +
            mred[threadIdx.x][2] + mred[threadIdx.x][3];
}

// ---------------------------------------------------------------------------
// FUSED: blocks 0..19 = redhist (one bin/thread, 256 coalesced loads);
//        block 20     = solveA (BN1 closed form from mpart -> p1).
// ---------------------------------------------------------------------------
__global__ __launch_bounds__(256) void redA_kernel(const unsigned* __restrict__ partial,
                                                   float* __restrict__ histf,
                                                   const float* __restrict__ mpart,
                                                   const float* __restrict__ w2,
                                                   const float* __restrict__ b2,
                                                   const float* __restrict__ g1,
                                                   const float* __restrict__ bb1,
                                                   float* __restrict__ p1) {
    if (blockIdx.x < 20) {
        int bin = blockIdx.x * 256 + threadIdx.x;
        if (bin >= 4913) return;
        unsigned s = 0;
        for (int blk = 0; blk < 256; ++blk) s += partial[blk * 4913 + bin];
        histf[bin] = (float)s;
        return;
    }
    // ---- solveA (block 20) ----
    __shared__ float mom[27];
    int t = threadIdx.x;
    if (t < 27) {
        float s = 0.f;
        for (int blk = 0; blk < 256; ++blk) s += mpart[blk * 27 + t];
        mom[t] = s;
    }
    __syncthreads();
    if (t < 32) {
        float w2r[6];
        #pragma unroll
        for (int k = 0; k < 6; ++k) w2r[k] = w2[t * 6 + k];
        float b2c = b2[t];
        float wm1 = 0.f;
        #pragma unroll
        for (int k = 0; k < 6; ++k) wm1 += w2r[k] * mom[k];
        float q = 0.f;
        int ii = 6;
        #pragma unroll
        for (int j = 0; j < 6; ++j)
            #pragma unroll
            for (int k = j; k < 6; ++k) {
                float f = w2r[j] * w2r[k] * mom[ii];
                q += (j == k) ? f : 2.f * f;
                ++ii;
            }
        float mean = b2c + wm1 / NPIXF;
        float ex2 = b2c * b2c + 2.f * b2c * (wm1 / NPIXF) + q / NPIXF;
        float var = ex2 - mean * mean;
        float a = g1[t] * rsqrtf(var + 1e-5f);
        p1[t] = a;
        p1[32 + t] = bb1[t] - mean * a;
    }
}

// ---------------------------------------------------------------------------
// FUSED solveB+fin2: one block per channel c; sweeps all 4913 bins, reduces,
// thread 0 finalizes p2[c].
// ---------------------------------------------------------------------------
__global__ __launch_bounds__(256) void solveB2_kernel(const float* __restrict__ histf,
                                                      const float* __restrict__ w1,
                                                      const float* __restrict__ b1,
                                                      const float* __restrict__ w2,
                                                      const float* __restrict__ b2,
                                                      const float* __restrict__ p1,
                                                      const float* __restrict__ w3,
                                                      const float* __restrict__ b3,
                                                      const float* __restrict__ g,
                                                      const float* __restrict__ bb,
                                                      float* __restrict__ p2) {
    __shared__ float rs[4], rq[4];
    int c = blockIdx.x;
    float w1r[18], b1r[6], w2r[6];
    #pragma unroll
    for (int k = 0; k < 18; ++k) w1r[k] = w1[k];
    #pragma unroll
    for (int o = 0; o < 6; ++o) b1r[o] = b1[o];
    #pragma unroll
    for (int k = 0; k < 6; ++k) w2r[k] = w2[c * 6 + k];
    float b2c = b2[c];
    float a1 = p1[c], c1 = p1[32 + c];
    float sm = 0.f, sq = 0.f;
    for (int bin = threadIdx.x; bin < 4913; bin += 256) {
        float cnt = histf[bin];
        int k0 = bin % 17;
        int r = bin / 17;
        int k1 = r % 17;
        int k2 = r / 17;
        float xm0 = k0 * 0.0625f, xm1 = k1 * 0.0625f, xm2 = k2 * 0.0625f;
        float t1[6];
        #pragma unroll
        for (int o = 0; o < 6; ++o)
            t1[o] = leaky(xm0 * w1r[o * 3] + xm1 * w1r[o * 3 + 1] + xm2 * w1r[o * 3 + 2] + b1r[o]);
        float h2 = b2c;
        #pragma unroll
        for (int k = 0; k < 6; ++k) h2 += w2r[k] * t1[k];
        float tt = leaky(a1 * h2 + c1);
        sm += cnt * tt;
        sq += cnt * tt * tt;
    }
    #pragma unroll
    for (int off = 32; off >= 1; off >>= 1) {
        sm += __shfl_xor(sm, off);
        sq += __shfl_xor(sq, off);
    }
    if ((threadIdx.x & 63) == 0) { rs[threadIdx.x >> 6] = sm; rq[threadIdx.x >> 6] = sq; }
    __syncthreads();
    if (threadIdx.x == 0) {
        float s = rs[0] + rs[1] + rs[2] + rs[3];
        float qq = rq[0] + rq[1] + rq[2] + rq[3];
        float mt = s / NPIXF;
        float vt = qq / NPIXF - mt * mt;
        float m2 = w3[c] * mt + b3[c];
        float v2 = w3[c] * w3[c] * vt;
        float a = g[c] * rsqrtf(v2 + 1e-5f);
        p2[c] = a;
        p2[32 + c] = bb[c] - m2 * a;
    }
}

// ---------------------------------------------------------------------------
// Level-1 downsample fused with prepare chain (round-5 proven).
// ---------------------------------------------------------------------------
__global__ __launch_bounds__(64) void d1_kernel(const unsigned char* __restrict__ modeq,
                                                const float* __restrict__ w1,
                                                const float* __restrict__ b1,
                                                const float* __restrict__ w2,
                                                const float* __restrict__ b2,
                                                const float* __restrict__ w3,
                                                const float* __restrict__ b3,
                                                const float* __restrict__ p1,
                                                const float* __restrict__ p2,
                                                const float* __restrict__ kd,
                                                float* __restrict__ d1) {
    int j = blockIdx.x * 64 + threadIdx.x;
    if (j >= 171) return;
    int i = blockIdx.y;
    int b = blockIdx.z;
    float acc[32];
    #pragma unroll
    for (int c = 0; c < 32; ++c) acc[c] = 0.f;
    const unsigned char* mp = modeq + (size_t)b * 3 * HW;
    #pragma unroll
    for (int u = 0; u < 3; ++u) {
        int r = 3 * i - 1 + u;
        if (r < 0 || r > 511) continue;
        #pragma unroll
        for (int v = 0; v < 3; ++v) {
            int col = 3 * j - 1 + v;
            if (col < 0 || col > 511) continue;
            int off = r * WW + col;
            float xm0 = mp[off] * 0.0625f, xm1 = mp[off + HW] * 0.0625f, xm2 = mp[off + 2 * HW] * 0.0625f;
            float t1[6];
            #pragma unroll
            for (int o = 0; o < 6; ++o)
                t1[o] = leaky(xm0 * w1[o * 3] + xm1 * w1[o * 3 + 1] + xm2 * w1[o * 3 + 2] + b1[o]);
            #pragma unroll
            for (int c = 0; c < 32; ++c) {
                float h2 = b2[c];
                #pragma unroll
                for (int k = 0; k < 6; ++k) h2 += w2[c * 6 + k] * t1[k];
                float t = leaky(h2 * p1[c] + p1[32 + c]);
                float uu = t * w3[c] + b3[c];
                float hv = leaky(uu * p2[c] + p2[32 + c]);
                acc[c] += hv * kd[c * 9 + u * 3 + v];
            }
        }
    }
    size_t base = ((size_t)(b * 32) * 171 + i) * 171 + j;
    #pragma unroll
    for (int c = 0; c < 32; ++c) d1[base + (size_t)c * 29241] = acc[c];
}

// ---------------------------------------------------------------------------
// Fused pyramid tail: L1 stats + levels 2..6 + stats, pstats non-atomic.
// ---------------------------------------------------------------------------
__device__ __forceinline__ void red_store(float sm, float sq, float* rsc, float* ps) {
    #pragma unroll
    for (int off = 32; off >= 1; off >>= 1) {
        sm += __shfl_xor(sm, off);
        sq += __shfl_xor(sq, off);
    }
    __syncthreads();
    int wv = threadIdx.x >> 6;
    if ((threadIdx.x & 63) == 0) { rsc[wv] = sm; rsc[8 + wv] = sq; }
    __syncthreads();
    if (threadIdx.x == 0) {
        ps[0] = rsc[0] + rsc[1] + rsc[2] + rsc[3];
        ps[1] = rsc[8] + rsc[9] + rsc[10] + rsc[11];
    }
}

__device__ __forceinline__ void lvl(const float* src, int sin, float* dstL,
                                    float* dstG, int sout, const float* kreg,
                                    float* rsc, float* ps) {
    float sm = 0.f, sq = 0.f;
    int n = sout * sout;
    for (int i = threadIdx.x; i < n; i += 256) {
        int oi = i / sout, oj = i - oi * sout;
        float acc = 0.f;
        #pragma unroll
        for (int u = 0; u < 3; ++u) {
            int r = 3 * oi - 1 + u;
            if ((unsigned)r >= (unsigned)sin) continue;
            #pragma unroll
            for (int v = 0; v < 3; ++v) {
                int cc = 3 * oj - 1 + v;
                if ((unsigned)cc >= (unsigned)sin) continue;
                acc += src[r * sin + cc] * kreg[u * 3 + v];
            }
        }
        dstG[i] = acc;
        if (dstL) dstL[i] = acc;
        float w = repw(oi, sout) * repw(oj, sout);
        sm += w * acc;
        sq += w * acc * acc;
    }
    red_store(sm, sq, rsc, ps);
}

__global__ __launch_bounds__(256) void pyramid_kernel(const float* __restrict__ d1,
                                                      float* __restrict__ d2,
                                                      float* __restrict__ d3,
                                                      float* __restrict__ d4,
                                                      float* __restrict__ d5,
                                                      float* __restrict__ d6,
                                                      const float* __restrict__ kd,
                                                      float* __restrict__ pstats) {
    __shared__ float buf2[3249];
    __shared__ float buf3[361];
    __shared__ float buf4[49];
    __shared__ float buf5[9];
    __shared__ float rsc[16];
    int bc = blockIdx.x;
    int c = bc & 31;
    float kreg[9];
    #pragma unroll
    for (int qq = 0; qq < 9; ++qq) kreg[qq] = kd[c * 9 + qq];
    float* ps = pstats + (size_t)bc * 12;
    const float* s1 = d1 + (size_t)bc * 29241;
    float sm = 0.f, sq = 0.f;
    for (int i = threadIdx.x; i < 29241; i += 256) {
        int oi = i / 171, oj = i - oi * 171;
        float w = repw(oi, 171) * repw(oj, 171);
        float v = s1[i];
        sm += w * v;
        sq += w * v * v;
    }
    red_store(sm, sq, rsc, ps + 0);
    lvl(s1, 171, buf2, d2 + (size_t)bc * 3249, 57, kreg, rsc, ps + 2);
    lvl(buf2, 57, buf3, d3 + (size_t)bc * 361, 19, kreg, rsc, ps + 4);
    lvl(buf3, 19, buf4, d4 + (size_t)bc * 49, 7, kreg, rsc, ps + 6);
    lvl(buf4, 7, buf5, d5 + (size_t)bc * 9, 3, kreg, rsc, ps + 8);
    lvl(buf5, 3, nullptr, d6 + bc, 1, kreg, rsc, ps + 10);
}

// Separate fin3 (round-5 proven shape), reading non-atomic pstats.
__global__ void fin3_kernel(const float* __restrict__ pstats, const float* __restrict__ kw,
                            const float* __restrict__ gw, const float* __restrict__ bw,
                            const float* __restrict__ kh, const float* __restrict__ gh,
                            const float* __restrict__ bh, float* __restrict__ lp) {
    int t = threadIdx.x;
    if (t >= 192) return;
    int l = t >> 5, c = t & 31;
    float sm = 0.f, sq = 0.f;
    #pragma unroll
    for (int b = 0; b < 4; ++b) {
        const float* ps = pstats + (size_t)(b * 32 + c) * 12 + 2 * l;
        sm += ps[0];
        sq += ps[1];
    }
    float mz = sm / NPIXF;
    float vz = sq / NPIXF - mz * mz;
    float kwc = kw[c];
    float aw = gw[c] * rsqrtf(kwc * kwc * vz + 1e-5f);
    float khc = kh[c];
    float ah = gh[c] * rsqrtf(khc * khc * vz + 1e-5f);
    float* o = lp + (size_t)(l * 32 + c) * 4;
    o[0] = kwc * aw;
    o[1] = bw[c] - kwc * mz * aw;
    o[2] = khc * ah;
    o[3] = bh[c] - khc * mz * ah;
}

// Final: grid-stride persistent form (2048 blocks x 16 chunks, proven
// neutral-vs-32768 in round 0). 4 px/thread, nontemporal f4 stores.
__global__ __launch_bounds__(256) void final_kernel(const float* __restrict__ d1,
                                                    const float* __restrict__ d2,
                                                    const float* __restrict__ d3,
                                                    const float* __restrict__ d4,
                                                    const float* __restrict__ d5,
                                                    const float* __restrict__ d6,
                                                    const float* __restrict__ lp,
                                                    float* __restrict__ out) {
    const float* ds[6] = {d1, d2, d3, d4, d5, d6};
    const int ss[6] = {171, 57, 19, 7, 3, 1};
    int idx = blockIdx.x * 256 + threadIdx.x;
    #pragma unroll 1
    for (int it = 0; it < 16; ++it, idx += 524288) {
        int w4 = (idx & 127) << 2;
        int h = (idx >> 7) & 511;
        int c = (idx >> 16) & 31;
        int b = idx >> 21;
        float accw[4] = {0.f, 0.f, 0.f, 0.f};
        float acch[4] = {0.f, 0.f, 0.f, 0.f};
        #pragma unroll
        for (int l = 0; l < 6; ++l) {
            int s = ss[l];
            int sh = (h * s) >> 9;
            const float* base = ds[l] + ((size_t)(b * 32 + c) * s + sh) * s;
            const float* a = lp + (size_t)(l * 32 + c) * 4;
            float a0 = a[0], a1 = a[1], a2 = a[2], a3 = a[3];
            #pragma unroll
            for (int k = 0; k < 4; ++k) {
                int sw = ((w4 + k) * s) >> 9;
                float val = base[sw];
                accw[k] += leaky(val * a0 + a1);
                acch[k] += leaky(val * a2 + a3);
            }
        }
        size_t o = (((size_t)(b * 64 + c)) << 18) + ((size_t)h << 9) + w4;
        f4 vw = {accw[0], accw[1], accw[2], accw[3]};
        f4 vh = {acch[0], acch[1], acch[2], acch[3]};
        __builtin_nontemporal_store(vw, (f4*)(out + o));
        __builtin_nontemporal_store(vh, (f4*)(out + o + (((size_t)32) << 18)));
    }
}

extern "C" void kernel_launch(void* const* d_in, const int* in_sizes, int n_in,
                              void* d_out, int out_size, void* d_ws, size_t ws_size,
                              hipStream_t stream) {
    const float* x     = (const float*)d_in[0];
    const float* w1    = (const float*)d_in[1];
    const float* b1    = (const float*)d_in[2];
    const float* w2    = (const float*)d_in[3];
    const float* b2    = (const float*)d_in[4];
    const float* bn1g  = (const float*)d_in[5];
    const float* bn1b  = (const float*)d_in[6];
    const float* w3    = (const float*)d_in[7];
    const float* b3    = (const float*)d_in[8];
    const float* bn2g  = (const float*)d_in[9];
    const float* bn2b  = (const float*)d_in[10];
    const float* kd    = (const float*)d_in[11];
    const float* kw    = (const float*)d_in[12];
    const float* bnwg  = (const float*)d_in[13];
    const float* bnwb  = (const float*)d_in[14];
    const float* kh    = (const float*)d_in[15];
    const float* bnhg  = (const float*)d_in[16];
    const float* bnhb  = (const float*)d_in[17];
    float* out = (float*)d_out;

    char* ws = (char*)d_ws;
    unsigned char* modeq = (unsigned char*)ws;             // 3,145,728 B
    float* mpart  = (float*)(ws + 3145728);                // 256*27 f = 27,648 B
    float* pstats = (float*)(ws + 3145728 + 27648);        // 128*12 f = 6,144 B
    float* p1 = (float*)(ws + 3179520);                    // 64 f
    float* p2 = p1 + 64;                                   // 64 f
    float* lp = p2 + 64;                                   // 768 f
    float* histf = (float*)(ws + 3183104);                 // 4913 f (pad to 19,968 B)
    unsigned* partial = (unsigned*)(ws + 3183104 + 19968); // 256*4913 u32 = 5,030,912 B
    float* d1 = (float*)(ws + 3203072 + 5030912);          // 3,742,848 f (off 8,233,984)
    float* d2 = d1 + 3742848;                              // 415,872 f
    float* d3 = d2 + 415872;                               // 46,208 f
    float* d4 = d3 + 46208;                                // 6,272 f
    float* d5 = d4 + 6272;                                 // 1,152 f
    float* d6 = d5 + 1152;                                 // 128 f

    mode_kernel<<<dim3(2, 32, 12), 256, 0, stream>>>(x, modeq);
    hist_kernel<<<256, 256, 0, stream>>>(modeq, w1, b1, partial, mpart);
    redA_kernel<<<21, 256, 0, stream>>>(partial, histf, mpart, w2, b2, bn1g, bn1b, p1);
    solveB2_kernel<<<32, 256, 0, stream>>>(histf, w1, b1, w2, b2, p1,
                                           w3, b3, bn2g, bn2b, p2);
    d1_kernel<<<dim3(3, 171, 4), 64, 0, stream>>>(modeq, w1, b1, w2, b2, w3, b3,
                                                  p1, p2, kd, d1);
    pyramid_kernel<<<128, 256, 0, stream>>>(d1, d2, d3, d4, d5, d6, kd, pstats);
    fin3_kernel<<<1, 192, 0, stream>>>(pstats, kw, bnwg, bnwb, kh, bnhg, bnhb, lp);
    final_kernel<<<2048, 256, 0, stream>>>(d1, d2, d3, d4, d5, d6, lp, out);
}

// Round 3
// 461.884 us; speedup vs baseline: 1.0577x; 1.0577x over previous
//
#include <hip/hip_runtime.h>

#define HH 512
#define WW 512
#define HW 262144          // 512*512
#define NPIX 1048576       // 4*512*512
#define NPIXF 1048576.0f

typedef float f4 __attribute__((ext_vector_type(4)));

__device__ __forceinline__ float leaky(float v) { return v > 0.f ? v : 0.01f * v; }

// replication count of source index i at level size s (nearest upsample to 512)
__device__ __forceinline__ float repw(int i, int s) {
    return (float)(((i + 1) * 512 + s - 1) / s - (i * 512 + s - 1) / s);
}

// 17 bins as 7-bit fields: vals 0..8 in h0 (bits 7*v), vals 9..16 in h1
// (bits 7*(v-9)). Max window count 121 < 128 so fields never carry.
// shift = 7*val for lo, 7*val-63 for hi; note -63 == +1 (mod 64).
__device__ __forceinline__ void hins7(unsigned long long& h0, unsigned long long& h1,
                                      int val) {
    int lo = val < 9;
    unsigned long long inc = 1ull << ((val * 7 + (lo ? 0 : 1)) & 63);
    h0 += lo ? inc : 0ull;
    h1 += lo ? 0ull : inc;
}
__device__ __forceinline__ void hrem7(unsigned long long& h0, unsigned long long& h1,
                                      int val) {
    int lo = val < 9;
    unsigned long long inc = 1ull << ((val * 7 + (lo ? 0 : 1)) & 63);
    h0 -= lo ? inc : 0ull;
    h1 -= lo ? 0ull : inc;
}

// ---------------------------------------------------------------------------
// Mode pooling v5: v3's proven data flow (per-thread column histogram slid
// vertically, double-buffered LDS mirror, one barrier per row) with the
// column histogram repacked from 5 u32 to 4 u32 (7-bit fields, 2xu64).
// The 11-column gather is now 11x ds_read_b128 (16B-aligned, sequential,
// conflict-free) instead of 33 mixed b64/b32 reads. Tie-break scan unchanged.
// ---------------------------------------------------------------------------
__global__ __launch_bounds__(256) void mode_kernel(const float* __restrict__ x,
                                                   unsigned char* __restrict__ modeq) {
    __shared__ unsigned char q[26 * 272];
    __shared__ __align__(16) unsigned ch[2][267 * 4];
    const int plane = blockIdx.z;
    const int tc0 = blockIdx.x * 256;
    const int tr0 = blockIdx.y * 16;
    const float* xp = x + (size_t)plane * HW;
    for (int idx = threadIdx.x; idx < 26 * 266; idx += 256) {
        int r = idx / 266;
        int cc = idx - r * 266;
        int gr = tr0 + r - 5; gr = gr < 0 ? -gr : (gr > 511 ? 1022 - gr : gr);
        int gc = tc0 + cc - 5; gc = gc < 0 ? -gc : (gc > 511 ? 1022 - gc : gc);
        float v = rintf(xp[gr * WW + gc] * 15.9375f);   // 255/16, round-half-even
        v = fminf(fmaxf(v, 0.f), 16.f);
        q[r * 272 + cc] = (unsigned char)(int)v;
    }
    const int t = threadIdx.x;
    unsigned long long A0 = 0, A1 = 0;
    unsigned long long B0 = 0, B1 = 0;
    __syncthreads();
    for (int r = 0; r < 16; ++r) {
        if (r == 0) {
            #pragma unroll
            for (int v = 0; v < 11; ++v) {
                hins7(A0, A1, q[v * 272 + t]);
                if (t < 10) hins7(B0, B1, q[v * 272 + 256 + t]);
            }
        } else {
            hrem7(A0, A1, q[(r - 1) * 272 + t]);
            hins7(A0, A1, q[(r + 10) * 272 + t]);
            if (t < 10) {
                hrem7(B0, B1, q[(r - 1) * 272 + 256 + t]);
                hins7(B0, B1, q[(r + 10) * 272 + 256 + t]);
            }
        }
        unsigned* cb = ch[r & 1];
        cb[t * 4 + 0] = (unsigned)A0;
        cb[t * 4 + 1] = (unsigned)(A0 >> 32);
        cb[t * 4 + 2] = (unsigned)A1;
        cb[t * 4 + 3] = (unsigned)(A1 >> 32);
        if (t < 10) {
            cb[(256 + t) * 4 + 0] = (unsigned)B0;
            cb[(256 + t) * 4 + 1] = (unsigned)(B0 >> 32);
            cb[(256 + t) * 4 + 2] = (unsigned)B1;
            cb[(256 + t) * 4 + 3] = (unsigned)(B1 >> 32);
        }
        __syncthreads();
        unsigned long long H0 = 0, H1 = 0;
        #pragma unroll
        for (int v = 0; v < 11; ++v) {
            const unsigned* p = &cb[(t + v) * 4];
            H0 += (unsigned long long)p[0] | ((unsigned long long)p[1] << 32);
            H1 += (unsigned long long)p[2] | ((unsigned long long)p[3] << 32);
        }
        unsigned m = 0;
        #pragma unroll
        for (int i = 0; i < 9; ++i) {
            unsigned cnt = (unsigned)(H0 >> (7 * i)) & 0x7Fu;
            unsigned val = (cnt << 8) | (unsigned)(16 - i);
            m = m > val ? m : val;
        }
        #pragma unroll
        for (int i = 9; i < 17; ++i) {
            unsigned cnt = (unsigned)(H1 >> (7 * (i - 9))) & 0x7Fu;
            unsigned val = (cnt << 8) | (unsigned)(16 - i);
            m = m > val ? m : val;
        }
        int k = 16 - (int)(m & 0xFFu);
        modeq[(size_t)plane * HW + (size_t)(tr0 + r) * WW + tc0 + t] = (unsigned char)k;
    }
}

// ---------------------------------------------------------------------------
// Joint histogram + per-block t1 moments (non-atomic mpart). 128 blocks,
// 8192 px each (proven; 256 blocks doubled fixed cost and regressed).
// ---------------------------------------------------------------------------
__global__ __launch_bounds__(256) void hist_kernel(const unsigned char* __restrict__ modeq,
                                                   const float* __restrict__ w1,
                                                   const float* __restrict__ b1,
                                                   unsigned* __restrict__ partial,
                                                   float* __restrict__ mpart) {
    __shared__ unsigned lh[4913];
    __shared__ float mred[27][4];
    for (int i = threadIdx.x; i < 4913; i += 256) lh[i] = 0;
    __syncthreads();
    int base = blockIdx.x * 8192;
    int b = base >> 18;
    int hw0 = base & (HW - 1);
    const unsigned char* mp = modeq + (size_t)b * 3 * HW;
    #pragma unroll
    for (int j = 0; j < 8; ++j) {
        int g = threadIdx.x + 256 * j;
        int hw = hw0 + g * 4;
        unsigned u0 = *(const unsigned*)(mp + hw);
        unsigned u1 = *(const unsigned*)(mp + hw + HW);
        unsigned u2 = *(const unsigned*)(mp + hw + 2 * HW);
        #pragma unroll
        for (int k = 0; k < 4; ++k) {
            int k0 = (u0 >> (8 * k)) & 0xFF;
            int k1 = (u1 >> (8 * k)) & 0xFF;
            int k2 = (u2 >> (8 * k)) & 0xFF;
            atomicAdd(&lh[k0 + 17 * k1 + 289 * k2], 1u);
        }
    }
    __syncthreads();
    unsigned* pp = partial + blockIdx.x * 4913;
    for (int i = threadIdx.x; i < 4913; i += 256) pp[i] = lh[i];
    float w1r[18], b1r[6];
    #pragma unroll
    for (int k = 0; k < 18; ++k) w1r[k] = w1[k];
    #pragma unroll
    for (int o = 0; o < 6; ++o) b1r[o] = b1[o];
    float M[27];
    #pragma unroll
    for (int i = 0; i < 27; ++i) M[i] = 0.f;
    for (int bin = threadIdx.x; bin < 4913; bin += 256) {
        float cnt = (float)lh[bin];
        int k0 = bin % 17;
        int r = bin / 17;
        int k1 = r % 17;
        int k2 = r / 17;
        float xm0 = k0 * 0.0625f, xm1 = k1 * 0.0625f, xm2 = k2 * 0.0625f;
        float t1[6];
        #pragma unroll
        for (int o = 0; o < 6; ++o)
            t1[o] = leaky(xm0 * w1r[o * 3] + xm1 * w1r[o * 3 + 1] + xm2 * w1r[o * 3 + 2] + b1r[o]);
        #pragma unroll
        for (int o = 0; o < 6; ++o) M[o] += cnt * t1[o];
        int ii = 6;
        #pragma unroll
        for (int j = 0; j < 6; ++j)
            #pragma unroll
            for (int k = j; k < 6; ++k) { M[ii] += cnt * t1[j] * t1[k]; ++ii; }
    }
    int wv = threadIdx.x >> 6;
    #pragma unroll
    for (int i = 0; i < 27; ++i) {
        float v = M[i];
        #pragma unroll
        for (int off = 32; off >= 1; off >>= 1) v += __shfl_xor(v, off);
        if ((threadIdx.x & 63) == 0) mred[i][wv] = v;
    }
    __syncthreads();
    if (threadIdx.x < 27)
        mpart[blockIdx.x * 27 + threadIdx.x] =
            mred[threadIdx.x][0] + mred[threadIdx.x][1] +
            mred[threadIdx.x][2] + mred[threadIdx.x][3];
}

// ---------------------------------------------------------------------------
// FUSED: blocks 0..19 = redhist (one bin/thread, 128 coalesced loads);
//        block 20     = solveA (BN1 closed form from mpart -> p1).
// ---------------------------------------------------------------------------
__global__ __launch_bounds__(256) void redA_kernel(const unsigned* __restrict__ partial,
                                                   float* __restrict__ histf,
                                                   const float* __restrict__ mpart,
                                                   const float* __restrict__ w2,
                                                   const float* __restrict__ b2,
                                                   const float* __restrict__ g1,
                                                   const float* __restrict__ bb1,
                                                   float* __restrict__ p1) {
    if (blockIdx.x < 20) {
        int bin = blockIdx.x * 256 + threadIdx.x;
        if (bin >= 4913) return;
        unsigned s = 0;
        for (int blk = 0; blk < 128; ++blk) s += partial[blk * 4913 + bin];
        histf[bin] = (float)s;
        return;
    }
    // ---- solveA (block 20) ----
    __shared__ float mom[27];
    int t = threadIdx.x;
    if (t < 27) {
        float s = 0.f;
        for (int blk = 0; blk < 128; ++blk) s += mpart[blk * 27 + t];
        mom[t] = s;
    }
    __syncthreads();
    if (t < 32) {
        float w2r[6];
        #pragma unroll
        for (int k = 0; k < 6; ++k) w2r[k] = w2[t * 6 + k];
        float b2c = b2[t];
        float wm1 = 0.f;
        #pragma unroll
        for (int k = 0; k < 6; ++k) wm1 += w2r[k] * mom[k];
        float q = 0.f;
        int ii = 6;
        #pragma unroll
        for (int j = 0; j < 6; ++j)
            #pragma unroll
            for (int k = j; k < 6; ++k) {
                float f = w2r[j] * w2r[k] * mom[ii];
                q += (j == k) ? f : 2.f * f;
                ++ii;
            }
        float mean = b2c + wm1 / NPIXF;
        float ex2 = b2c * b2c + 2.f * b2c * (wm1 / NPIXF) + q / NPIXF;
        float var = ex2 - mean * mean;
        float a = g1[t] * rsqrtf(var + 1e-5f);
        p1[t] = a;
        p1[32 + t] = bb1[t] - mean * a;
    }
}

// ---------------------------------------------------------------------------
// FUSED solveB+fin2: one block per channel c; sweeps all 4913 bins, reduces,
// thread 0 finalizes p2[c].
// ---------------------------------------------------------------------------
__global__ __launch_bounds__(256) void solveB2_kernel(const float* __restrict__ histf,
                                                      const float* __restrict__ w1,
                                                      const float* __restrict__ b1,
                                                      const float* __restrict__ w2,
                                                      const float* __restrict__ b2,
                                                      const float* __restrict__ p1,
                                                      const float* __restrict__ w3,
                                                      const float* __restrict__ b3,
                                                      const float* __restrict__ g,
                                                      const float* __restrict__ bb,
                                                      float* __restrict__ p2) {
    __shared__ float rs[4], rq[4];
    int c = blockIdx.x;
    float w1r[18], b1r[6], w2r[6];
    #pragma unroll
    for (int k = 0; k < 18; ++k) w1r[k] = w1[k];
    #pragma unroll
    for (int o = 0; o < 6; ++o) b1r[o] = b1[o];
    #pragma unroll
    for (int k = 0; k < 6; ++k) w2r[k] = w2[c * 6 + k];
    float b2c = b2[c];
    float a1 = p1[c], c1 = p1[32 + c];
    float sm = 0.f, sq = 0.f;
    for (int bin = threadIdx.x; bin < 4913; bin += 256) {
        float cnt = histf[bin];
        int k0 = bin % 17;
        int r = bin / 17;
        int k1 = r % 17;
        int k2 = r / 17;
        float xm0 = k0 * 0.0625f, xm1 = k1 * 0.0625f, xm2 = k2 * 0.0625f;
        float t1[6];
        #pragma unroll
        for (int o = 0; o < 6; ++o)
            t1[o] = leaky(xm0 * w1r[o * 3] + xm1 * w1r[o * 3 + 1] + xm2 * w1r[o * 3 + 2] + b1r[o]);
        float h2 = b2c;
        #pragma unroll
        for (int k = 0; k < 6; ++k) h2 += w2r[k] * t1[k];
        float tt = leaky(a1 * h2 + c1);
        sm += cnt * tt;
        sq += cnt * tt * tt;
    }
    #pragma unroll
    for (int off = 32; off >= 1; off >>= 1) {
        sm += __shfl_xor(sm, off);
        sq += __shfl_xor(sq, off);
    }
    if ((threadIdx.x & 63) == 0) { rs[threadIdx.x >> 6] = sm; rq[threadIdx.x >> 6] = sq; }
    __syncthreads();
    if (threadIdx.x == 0) {
        float s = rs[0] + rs[1] + rs[2] + rs[3];
        float qq = rq[0] + rq[1] + rq[2] + rq[3];
        float mt = s / NPIXF;
        float vt = qq / NPIXF - mt * mt;
        float m2 = w3[c] * mt + b3[c];
        float v2 = w3[c] * w3[c] * vt;
        float a = g[c] * rsqrtf(v2 + 1e-5f);
        p2[c] = a;
        p2[32 + c] = bb[c] - m2 * a;
    }
}

// ---------------------------------------------------------------------------
// Level-1 downsample fused with prepare chain (round-5 proven).
// ---------------------------------------------------------------------------
__global__ __launch_bounds__(64) void d1_kernel(const unsigned char* __restrict__ modeq,
                                                const float* __restrict__ w1,
                                                const float* __restrict__ b1,
                                                const float* __restrict__ w2,
                                                const float* __restrict__ b2,
                                                const float* __restrict__ w3,
                                                const float* __restrict__ b3,
                                                const float* __restrict__ p1,
                                                const float* __restrict__ p2,
                                                const float* __restrict__ kd,
                                                float* __restrict__ d1) {
    int j = blockIdx.x * 64 + threadIdx.x;
    if (j >= 171) return;
    int i = blockIdx.y;
    int b = blockIdx.z;
    float acc[32];
    #pragma unroll
    for (int c = 0; c < 32; ++c) acc[c] = 0.f;
    const unsigned char* mp = modeq + (size_t)b * 3 * HW;
    #pragma unroll
    for (int u = 0; u < 3; ++u) {
        int r = 3 * i - 1 + u;
        if (r < 0 || r > 511) continue;
        #pragma unroll
        for (int v = 0; v < 3; ++v) {
            int col = 3 * j - 1 + v;
            if (col < 0 || col > 511) continue;
            int off = r * WW + col;
            float xm0 = mp[off] * 0.0625f, xm1 = mp[off + HW] * 0.0625f, xm2 = mp[off + 2 * HW] * 0.0625f;
            float t1[6];
            #pragma unroll
            for (int o = 0; o < 6; ++o)
                t1[o] = leaky(xm0 * w1[o * 3] + xm1 * w1[o * 3 + 1] + xm2 * w1[o * 3 + 2] + b1[o]);
            #pragma unroll
            for (int c = 0; c < 32; ++c) {
                float h2 = b2[c];
                #pragma unroll
                for (int k = 0; k < 6; ++k) h2 += w2[c * 6 + k] * t1[k];
                float t = leaky(h2 * p1[c] + p1[32 + c]);
                float uu = t * w3[c] + b3[c];
                float hv = leaky(uu * p2[c] + p2[32 + c]);
                acc[c] += hv * kd[c * 9 + u * 3 + v];
            }
        }
    }
    size_t base = ((size_t)(b * 32) * 171 + i) * 171 + j;
    #pragma unroll
    for (int c = 0; c < 32; ++c) d1[base + (size_t)c * 29241] = acc[c];
}

// ---------------------------------------------------------------------------
// Fused pyramid tail: L1 stats + levels 2..6 + stats, pstats non-atomic.
// ---------------------------------------------------------------------------
__device__ __forceinline__ void red_store(float sm, float sq, float* rsc, float* ps) {
    #pragma unroll
    for (int off = 32; off >= 1; off >>= 1) {
        sm += __shfl_xor(sm, off);
        sq += __shfl_xor(sq, off);
    }
    __syncthreads();
    int wv = threadIdx.x >> 6;
    if ((threadIdx.x & 63) == 0) { rsc[wv] = sm; rsc[8 + wv] = sq; }
    __syncthreads();
    if (threadIdx.x == 0) {
        ps[0] = rsc[0] + rsc[1] + rsc[2] + rsc[3];
        ps[1] = rsc[8] + rsc[9] + rsc[10] + rsc[11];
    }
}

__device__ __forceinline__ void lvl(const float* src, int sin, float* dstL,
                                    float* dstG, int sout, const float* kreg,
                                    float* rsc, float* ps) {
    float sm = 0.f, sq = 0.f;
    int n = sout * sout;
    for (int i = threadIdx.x; i < n; i += 256) {
        int oi = i / sout, oj = i - oi * sout;
        float acc = 0.f;
        #pragma unroll
        for (int u = 0; u < 3; ++u) {
            int r = 3 * oi - 1 + u;
            if ((unsigned)r >= (unsigned)sin) continue;
            #pragma unroll
            for (int v = 0; v < 3; ++v) {
                int cc = 3 * oj - 1 + v;
                if ((unsigned)cc >= (unsigned)sin) continue;
                acc += src[r * sin + cc] * kreg[u * 3 + v];
            }
        }
        dstG[i] = acc;
        if (dstL) dstL[i] = acc;
        float w = repw(oi, sout) * repw(oj, sout);
        sm += w * acc;
        sq += w * acc * acc;
    }
    red_store(sm, sq, rsc, ps);
}

__global__ __launch_bounds__(256) void pyramid_kernel(const float* __restrict__ d1,
                                                      float* __restrict__ d2,
                                                      float* __restrict__ d3,
                                                      float* __restrict__ d4,
                                                      float* __restrict__ d5,
                                                      float* __restrict__ d6,
                                                      const float* __restrict__ kd,
                                                      float* __restrict__ pstats) {
    __shared__ float buf2[3249];
    __shared__ float buf3[361];
    __shared__ float buf4[49];
    __shared__ float buf5[9];
    __shared__ float rsc[16];
    int bc = blockIdx.x;
    int c = bc & 31;
    float kreg[9];
    #pragma unroll
    for (int qq = 0; qq < 9; ++qq) kreg[qq] = kd[c * 9 + qq];
    float* ps = pstats + (size_t)bc * 12;
    const float* s1 = d1 + (size_t)bc * 29241;
    float sm = 0.f, sq = 0.f;
    for (int i = threadIdx.x; i < 29241; i += 256) {
        int oi = i / 171, oj = i - oi * 171;
        float w = repw(oi, 171) * repw(oj, 171);
        float v = s1[i];
        sm += w * v;
        sq += w * v * v;
    }
    red_store(sm, sq, rsc, ps + 0);
    lvl(s1, 171, buf2, d2 + (size_t)bc * 3249, 57, kreg, rsc, ps + 2);
    lvl(buf2, 57, buf3, d3 + (size_t)bc * 361, 19, kreg, rsc, ps + 4);
    lvl(buf3, 19, buf4, d4 + (size_t)bc * 49, 7, kreg, rsc, ps + 6);
    lvl(buf4, 7, buf5, d5 + (size_t)bc * 9, 3, kreg, rsc, ps + 8);
    lvl(buf5, 3, nullptr, d6 + bc, 1, kreg, rsc, ps + 10);
}

// Separate fin3 (round-5 proven shape), reading non-atomic pstats.
__global__ void fin3_kernel(const float* __restrict__ pstats, const float* __restrict__ kw,
                            const float* __restrict__ gw, const float* __restrict__ bw,
                            const float* __restrict__ kh, const float* __restrict__ gh,
                            const float* __restrict__ bh, float* __restrict__ lp) {
    int t = threadIdx.x;
    if (t >= 192) return;
    int l = t >> 5, c = t & 31;
    float sm = 0.f, sq = 0.f;
    #pragma unroll
    for (int b = 0; b < 4; ++b) {
        const float* ps = pstats + (size_t)(b * 32 + c) * 12 + 2 * l;
        sm += ps[0];
        sq += ps[1];
    }
    float mz = sm / NPIXF;
    float vz = sq / NPIXF - mz * mz;
    float kwc = kw[c];
    float aw = gw[c] * rsqrtf(kwc * kwc * vz + 1e-5f);
    float khc = kh[c];
    float ah = gh[c] * rsqrtf(khc * khc * vz + 1e-5f);
    float* o = lp + (size_t)(l * 32 + c) * 4;
    o[0] = kwc * aw;
    o[1] = bw[c] - kwc * mz * aw;
    o[2] = khc * ah;
    o[3] = bh[c] - khc * mz * ah;
}

// Final: grid-stride persistent form (proven neutral vs 32768 blocks).
// 4 px/thread, nontemporal f4 stores.
__global__ __launch_bounds__(256) void final_kernel(const float* __restrict__ d1,
                                                    const float* __restrict__ d2,
                                                    const float* __restrict__ d3,
                                                    const float* __restrict__ d4,
                                                    const float* __restrict__ d5,
                                                    const float* __restrict__ d6,
                                                    const float* __restrict__ lp,
                                                    float* __restrict__ out) {
    const float* ds[6] = {d1, d2, d3, d4, d5, d6};
    const int ss[6] = {171, 57, 19, 7, 3, 1};
    int idx = blockIdx.x * 256 + threadIdx.x;
    #pragma unroll 1
    for (int it = 0; it < 16; ++it, idx += 524288) {
        int w4 = (idx & 127) << 2;
        int h = (idx >> 7) & 511;
        int c = (idx >> 16) & 31;
        int b = idx >> 21;
        float accw[4] = {0.f, 0.f, 0.f, 0.f};
        float acch[4] = {0.f, 0.f, 0.f, 0.f};
        #pragma unroll
        for (int l = 0; l < 6; ++l) {
            int s = ss[l];
            int sh = (h * s) >> 9;
            const float* base = ds[l] + ((size_t)(b * 32 + c) * s + sh) * s;
            const float* a = lp + (size_t)(l * 32 + c) * 4;
            float a0 = a[0], a1 = a[1], a2 = a[2], a3 = a[3];
            #pragma unroll
            for (int k = 0; k < 4; ++k) {
                int sw = ((w4 + k) * s) >> 9;
                float val = base[sw];
                accw[k] += leaky(val * a0 + a1);
                acch[k] += leaky(val * a2 + a3);
            }
        }
        size_t o = (((size_t)(b * 64 + c)) << 18) + ((size_t)h << 9) + w4;
        f4 vw = {accw[0], accw[1], accw[2], accw[3]};
        f4 vh = {acch[0], acch[1], acch[2], acch[3]};
        __builtin_nontemporal_store(vw, (f4*)(out + o));
        __builtin_nontemporal_store(vh, (f4*)(out + o + (((size_t)32) << 18)));
    }
}

extern "C" void kernel_launch(void* const* d_in, const int* in_sizes, int n_in,
                              void* d_out, int out_size, void* d_ws, size_t ws_size,
                              hipStream_t stream) {
    const float* x     = (const float*)d_in[0];
    const float* w1    = (const float*)d_in[1];
    const float* b1    = (const float*)d_in[2];
    const float* w2    = (const float*)d_in[3];
    const float* b2    = (const float*)d_in[4];
    const float* bn1g  = (const float*)d_in[5];
    const float* bn1b  = (const float*)d_in[6];
    const float* w3    = (const float*)d_in[7];
    const float* b3    = (const float*)d_in[8];
    const float* bn2g  = (const float*)d_in[9];
    const float* bn2b  = (const float*)d_in[10];
    const float* kd    = (const float*)d_in[11];
    const float* kw    = (const float*)d_in[12];
    const float* bnwg  = (const float*)d_in[13];
    const float* bnwb  = (const float*)d_in[14];
    const float* kh    = (const float*)d_in[15];
    const float* bnhg  = (const float*)d_in[16];
    const float* bnhb  = (const float*)d_in[17];
    float* out = (float*)d_out;

    char* ws = (char*)d_ws;
    unsigned char* modeq = (unsigned char*)ws;             // 3,145,728 B
    float* mpart  = (float*)(ws + 3145728);                // 128*27 f = 13,824 B
    float* pstats = (float*)(ws + 3145728 + 13824);        // 128*12 f = 6,144 B
    float* p1 = (float*)(ws + 3165696);                    // 64 f
    float* p2 = p1 + 64;                                   // 64 f
    float* lp = p2 + 64;                                   // 768 f
    float* histf = (float*)(ws + 3169280);                 // 4913 f (pad to 20,480 B)
    unsigned* partial = (unsigned*)(ws + 3169280 + 20480); // 128*4913 u32 = 2,515,456 B
    float* d1 = (float*)(ws + 3189760 + 2515456);          // 3,742,848 f
    float* d2 = d1 + 3742848;                              // 415,872 f
    float* d3 = d2 + 415872;                               // 46,208 f
    float* d4 = d3 + 46208;                                // 6,272 f
    float* d5 = d4 + 6272;                                 // 1,152 f
    float* d6 = d5 + 1152;                                 // 128 f

    mode_kernel<<<dim3(2, 32, 12), 256, 0, stream>>>(x, modeq);
    hist_kernel<<<128, 256, 0, stream>>>(modeq, w1, b1, partial, mpart);
    redA_kernel<<<21, 256, 0, stream>>>(partial, histf, mpart, w2, b2, bn1g, bn1b, p1);
    solveB2_kernel<<<32, 256, 0, stream>>>(histf, w1, b1, w2, b2, p1,
                                           w3, b3, bn2g, bn2b, p2);
    d1_kernel<<<dim3(3, 171, 4), 64, 0, stream>>>(modeq, w1, b1, w2, b2, w3, b3,
                                                  p1, p2, kd, d1);
    pyramid_kernel<<<128, 256, 0, stream>>>(d1, d2, d3, d4, d5, d6, kd, pstats);
    fin3_kernel<<<1, 192, 0, stream>>>(pstats, kw, bnwg, bnwb, kh, bnhg, bnhb, lp);
    final_kernel<<<2048, 256, 0, stream>>>(d1, d2, d3, d4, d5, d6, lp, out);
}

// Round 4
// 443.471 us; speedup vs baseline: 1.1017x; 1.0415x over previous
//
#include <hip/hip_runtime.h>

#define HH 512
#define WW 512
#define HW 262144          // 512*512
#define NPIX 1048576       // 4*512*512
#define NPIXF 1048576.0f

typedef float f4 __attribute__((ext_vector_type(4)));

__device__ __forceinline__ float leaky(float v) { return v > 0.f ? v : 0.01f * v; }

// replication count of source index i at level size s (nearest upsample to 512)
__device__ __forceinline__ float repw(int i, int s) {
    return (float)(((i + 1) * 512 + s - 1) / s - (i * 512 + s - 1) / s);
}

// 17 bins as 7-bit fields: vals 0..8 in h0 (bits 7*v), vals 9..16 in h1
// (bits 7*(v-9)). Max window count 121 < 128 so fields never carry.
__device__ __forceinline__ void hins7(unsigned long long& h0, unsigned long long& h1,
                                      int val) {
    int lo = val < 9;
    unsigned long long inc = 1ull << ((val * 7 + (lo ? 0 : 1)) & 63);
    h0 += lo ? inc : 0ull;
    h1 += lo ? 0ull : inc;
}
__device__ __forceinline__ void hrem7(unsigned long long& h0, unsigned long long& h1,
                                      int val) {
    int lo = val < 9;
    unsigned long long inc = 1ull << ((val * 7 + (lo ? 0 : 1)) & 63);
    h0 -= lo ? inc : 0ull;
    h1 -= lo ? 0ull : inc;
}

// ---------------------------------------------------------------------------
// Mode pooling v5 (round-3 proven, -6.4us): per-thread column histogram in
// 7-bit fields (4 u32 = one ds_read_b128), double-buffered LDS mirror.
// ---------------------------------------------------------------------------
__global__ __launch_bounds__(256) void mode_kernel(const float* __restrict__ x,
                                                   unsigned char* __restrict__ modeq) {
    __shared__ unsigned char q[26 * 272];
    __shared__ __align__(16) unsigned ch[2][267 * 4];
    const int plane = blockIdx.z;
    const int tc0 = blockIdx.x * 256;
    const int tr0 = blockIdx.y * 16;
    const float* xp = x + (size_t)plane * HW;
    for (int idx = threadIdx.x; idx < 26 * 266; idx += 256) {
        int r = idx / 266;
        int cc = idx - r * 266;
        int gr = tr0 + r - 5; gr = gr < 0 ? -gr : (gr > 511 ? 1022 - gr : gr);
        int gc = tc0 + cc - 5; gc = gc < 0 ? -gc : (gc > 511 ? 1022 - gc : gc);
        float v = rintf(xp[gr * WW + gc] * 15.9375f);   // 255/16, round-half-even
        v = fminf(fmaxf(v, 0.f), 16.f);
        q[r * 272 + cc] = (unsigned char)(int)v;
    }
    const int t = threadIdx.x;
    unsigned long long A0 = 0, A1 = 0;
    unsigned long long B0 = 0, B1 = 0;
    __syncthreads();
    for (int r = 0; r < 16; ++r) {
        if (r == 0) {
            #pragma unroll
            for (int v = 0; v < 11; ++v) {
                hins7(A0, A1, q[v * 272 + t]);
                if (t < 10) hins7(B0, B1, q[v * 272 + 256 + t]);
            }
        } else {
            hrem7(A0, A1, q[(r - 1) * 272 + t]);
            hins7(A0, A1, q[(r + 10) * 272 + t]);
            if (t < 10) {
                hrem7(B0, B1, q[(r - 1) * 272 + 256 + t]);
                hins7(B0, B1, q[(r + 10) * 272 + 256 + t]);
            }
        }
        unsigned* cb = ch[r & 1];
        cb[t * 4 + 0] = (unsigned)A0;
        cb[t * 4 + 1] = (unsigned)(A0 >> 32);
        cb[t * 4 + 2] = (unsigned)A1;
        cb[t * 4 + 3] = (unsigned)(A1 >> 32);
        if (t < 10) {
            cb[(256 + t) * 4 + 0] = (unsigned)B0;
            cb[(256 + t) * 4 + 1] = (unsigned)(B0 >> 32);
            cb[(256 + t) * 4 + 2] = (unsigned)B1;
            cb[(256 + t) * 4 + 3] = (unsigned)(B1 >> 32);
        }
        __syncthreads();
        unsigned long long H0 = 0, H1 = 0;
        #pragma unroll
        for (int v = 0; v < 11; ++v) {
            const unsigned* p = &cb[(t + v) * 4];
            H0 += (unsigned long long)p[0] | ((unsigned long long)p[1] << 32);
            H1 += (unsigned long long)p[2] | ((unsigned long long)p[3] << 32);
        }
        unsigned m = 0;
        #pragma unroll
        for (int i = 0; i < 9; ++i) {
            unsigned cnt = (unsigned)(H0 >> (7 * i)) & 0x7Fu;
            unsigned val = (cnt << 8) | (unsigned)(16 - i);
            m = m > val ? m : val;
        }
        #pragma unroll
        for (int i = 9; i < 17; ++i) {
            unsigned cnt = (unsigned)(H1 >> (7 * (i - 9))) & 0x7Fu;
            unsigned val = (cnt << 8) | (unsigned)(16 - i);
            m = m > val ? m : val;
        }
        int k = 16 - (int)(m & 0xFFu);
        modeq[(size_t)plane * HW + (size_t)(tr0 + r) * WW + tc0 + t] = (unsigned char)k;
    }
}

// ---------------------------------------------------------------------------
// Joint histogram only (moment sweep moved to solveB3 -- it was duplicated
// 128x here and is linear in counts, so it folds into the reduced histf).
// ---------------------------------------------------------------------------
__global__ __launch_bounds__(256) void hist_kernel(const unsigned char* __restrict__ modeq,
                                                   unsigned* __restrict__ partial) {
    __shared__ unsigned lh[4913];
    for (int i = threadIdx.x; i < 4913; i += 256) lh[i] = 0;
    __syncthreads();
    int base = blockIdx.x * 8192;
    int b = base >> 18;
    int hw0 = base & (HW - 1);
    const unsigned char* mp = modeq + (size_t)b * 3 * HW;
    #pragma unroll
    for (int j = 0; j < 8; ++j) {
        int g = threadIdx.x + 256 * j;
        int hw = hw0 + g * 4;
        unsigned u0 = *(const unsigned*)(mp + hw);
        unsigned u1 = *(const unsigned*)(mp + hw + HW);
        unsigned u2 = *(const unsigned*)(mp + hw + 2 * HW);
        #pragma unroll
        for (int k = 0; k < 4; ++k) {
            int k0 = (u0 >> (8 * k)) & 0xFF;
            int k1 = (u1 >> (8 * k)) & 0xFF;
            int k2 = (u2 >> (8 * k)) & 0xFF;
            atomicAdd(&lh[k0 + 17 * k1 + 289 * k2], 1u);
        }
    }
    __syncthreads();
    unsigned* pp = partial + blockIdx.x * 4913;
    for (int i = threadIdx.x; i < 4913; i += 256) pp[i] = lh[i];
}

// Pure redhist: one bin/thread, 128 coalesced loads. 20 blocks.
__global__ __launch_bounds__(256) void redhist_kernel(const unsigned* __restrict__ partial,
                                                      float* __restrict__ histf) {
    int bin = blockIdx.x * 256 + threadIdx.x;
    if (bin >= 4913) return;
    unsigned s = 0;
    for (int blk = 0; blk < 128; ++blk) s += partial[blk * 4913 + bin];
    histf[bin] = (float)s;
}

// ---------------------------------------------------------------------------
// FUSED solveA+solveB+fin2: one block per channel c.
// Pass A: sweep histf -> 27 moments (block-reduced) + cache per-bin h2 in LDS.
// Derive a1,c1 (BN1 closed form) -> write p1[c]. Pass B: t-stats from cached
// h2 -> p2[c]. Removes the 128x-duplicated moment sweep from hist_kernel.
// ---------------------------------------------------------------------------
__global__ __launch_bounds__(256) void solveB3_kernel(const float* __restrict__ histf,
                                                      const float* __restrict__ w1,
                                                      const float* __restrict__ b1,
                                                      const float* __restrict__ w2,
                                                      const float* __restrict__ b2,
                                                      const float* __restrict__ g1,
                                                      const float* __restrict__ bb1,
                                                      const float* __restrict__ w3,
                                                      const float* __restrict__ b3,
                                                      const float* __restrict__ g2,
                                                      const float* __restrict__ bb2,
                                                      float* __restrict__ p1,
                                                      float* __restrict__ p2) {
    __shared__ float h2s[4913];
    __shared__ float red[27][4];
    __shared__ float rs[4], rq[4];
    int c = blockIdx.x;
    float w1r[18], b1r[6], w2r[6];
    #pragma unroll
    for (int k = 0; k < 18; ++k) w1r[k] = w1[k];
    #pragma unroll
    for (int o = 0; o < 6; ++o) b1r[o] = b1[o];
    #pragma unroll
    for (int k = 0; k < 6; ++k) w2r[k] = w2[c * 6 + k];
    float b2c = b2[c];
    float M[27];
    #pragma unroll
    for (int i = 0; i < 27; ++i) M[i] = 0.f;
    for (int bin = threadIdx.x; bin < 4913; bin += 256) {
        float cnt = histf[bin];
        int k0 = bin % 17;
        int r = bin / 17;
        int k1 = r % 17;
        int k2 = r / 17;
        float xm0 = k0 * 0.0625f, xm1 = k1 * 0.0625f, xm2 = k2 * 0.0625f;
        float t1[6];
        #pragma unroll
        for (int o = 0; o < 6; ++o)
            t1[o] = leaky(xm0 * w1r[o * 3] + xm1 * w1r[o * 3 + 1] + xm2 * w1r[o * 3 + 2] + b1r[o]);
        float h2 = b2c;
        #pragma unroll
        for (int k = 0; k < 6; ++k) h2 += w2r[k] * t1[k];
        h2s[bin] = h2;   // each thread re-reads only its own bins: no barrier needed
        #pragma unroll
        for (int o = 0; o < 6; ++o) M[o] += cnt * t1[o];
        int ii = 6;
        #pragma unroll
        for (int j = 0; j < 6; ++j)
            #pragma unroll
            for (int k = j; k < 6; ++k) { M[ii] += cnt * t1[j] * t1[k]; ++ii; }
    }
    int wv = threadIdx.x >> 6;
    #pragma unroll
    for (int i = 0; i < 27; ++i) {
        float v = M[i];
        #pragma unroll
        for (int off = 32; off >= 1; off >>= 1) v += __shfl_xor(v, off);
        if ((threadIdx.x & 63) == 0) red[i][wv] = v;
    }
    __syncthreads();
    // BN1 closed form (computed redundantly by all threads; scalar chain)
    float wm1 = 0.f;
    #pragma unroll
    for (int k = 0; k < 6; ++k)
        wm1 += w2r[k] * (red[k][0] + red[k][1] + red[k][2] + red[k][3]);
    float qd = 0.f;
    int ii = 6;
    #pragma unroll
    for (int j = 0; j < 6; ++j)
        #pragma unroll
        for (int k = j; k < 6; ++k) {
            float mom = red[ii][0] + red[ii][1] + red[ii][2] + red[ii][3];
            float f = w2r[j] * w2r[k] * mom;
            qd += (j == k) ? f : 2.f * f;
            ++ii;
        }
    float mean = b2c + wm1 / NPIXF;
    float ex2 = b2c * b2c + 2.f * b2c * (wm1 / NPIXF) + qd / NPIXF;
    float var = ex2 - mean * mean;
    float a1 = g1[c] * rsqrtf(var + 1e-5f);
    float c1 = bb1[c] - mean * a1;
    if (threadIdx.x == 0) { p1[c] = a1; p1[32 + c] = c1; }
    // Pass B: t = leaky(a1*h2 + c1) stats from cached h2
    float sm = 0.f, sq = 0.f;
    for (int bin = threadIdx.x; bin < 4913; bin += 256) {
        float cnt = histf[bin];
        float tt = leaky(a1 * h2s[bin] + c1);
        sm += cnt * tt;
        sq += cnt * tt * tt;
    }
    #pragma unroll
    for (int off = 32; off >= 1; off >>= 1) {
        sm += __shfl_xor(sm, off);
        sq += __shfl_xor(sq, off);
    }
    if ((threadIdx.x & 63) == 0) { rs[wv] = sm; rq[wv] = sq; }
    __syncthreads();
    if (threadIdx.x == 0) {
        float s = rs[0] + rs[1] + rs[2] + rs[3];
        float qq = rq[0] + rq[1] + rq[2] + rq[3];
        float mt = s / NPIXF;
        float vt = qq / NPIXF - mt * mt;
        float m2 = w3[c] * mt + b3[c];
        float v2 = w3[c] * w3[c] * vt;
        float a = g2[c] * rsqrtf(v2 + 1e-5f);
        p2[c] = a;
        p2[32 + c] = bb2[c] - m2 * a;
    }
}

// ---------------------------------------------------------------------------
// Level-1 downsample fused with prepare chain. Now 192-thread blocks,
// grid (171,4): 684 blocks x 3 waves (~8 waves/CU, was 0.5 waves/SIMD).
// ---------------------------------------------------------------------------
__global__ __launch_bounds__(192) void d1_kernel(const unsigned char* __restrict__ modeq,
                                                 const float* __restrict__ w1,
                                                 const float* __restrict__ b1,
                                                 const float* __restrict__ w2,
                                                 const float* __restrict__ b2,
                                                 const float* __restrict__ w3,
                                                 const float* __restrict__ b3,
                                                 const float* __restrict__ p1,
                                                 const float* __restrict__ p2,
                                                 const float* __restrict__ kd,
                                                 float* __restrict__ d1) {
    int j = threadIdx.x;
    if (j >= 171) return;
    int i = blockIdx.x;
    int b = blockIdx.y;
    float acc[32];
    #pragma unroll
    for (int c = 0; c < 32; ++c) acc[c] = 0.f;
    const unsigned char* mp = modeq + (size_t)b * 3 * HW;
    #pragma unroll
    for (int u = 0; u < 3; ++u) {
        int r = 3 * i - 1 + u;
        if (r < 0 || r > 511) continue;
        #pragma unroll
        for (int v = 0; v < 3; ++v) {
            int col = 3 * j - 1 + v;
            if (col < 0 || col > 511) continue;
            int off = r * WW + col;
            float xm0 = mp[off] * 0.0625f, xm1 = mp[off + HW] * 0.0625f, xm2 = mp[off + 2 * HW] * 0.0625f;
            float t1[6];
            #pragma unroll
            for (int o = 0; o < 6; ++o)
                t1[o] = leaky(xm0 * w1[o * 3] + xm1 * w1[o * 3 + 1] + xm2 * w1[o * 3 + 2] + b1[o]);
            #pragma unroll
            for (int c = 0; c < 32; ++c) {
                float h2 = b2[c];
                #pragma unroll
                for (int k = 0; k < 6; ++k) h2 += w2[c * 6 + k] * t1[k];
                float t = leaky(h2 * p1[c] + p1[32 + c]);
                float uu = t * w3[c] + b3[c];
                float hv = leaky(uu * p2[c] + p2[32 + c]);
                acc[c] += hv * kd[c * 9 + u * 3 + v];
            }
        }
    }
    size_t base = ((size_t)(b * 32) * 171 + i) * 171 + j;
    #pragma unroll
    for (int c = 0; c < 32; ++c) d1[base + (size_t)c * 29241] = acc[c];
}

// ---------------------------------------------------------------------------
// Fused pyramid tail: L1 stats + levels 2..6 + stats, pstats non-atomic.
// ---------------------------------------------------------------------------
__device__ __forceinline__ void red_store(float sm, float sq, float* rsc, float* ps) {
    #pragma unroll
    for (int off = 32; off >= 1; off >>= 1) {
        sm += __shfl_xor(sm, off);
        sq += __shfl_xor(sq, off);
    }
    __syncthreads();
    int wv = threadIdx.x >> 6;
    if ((threadIdx.x & 63) == 0) { rsc[wv] = sm; rsc[8 + wv] = sq; }
    __syncthreads();
    if (threadIdx.x == 0) {
        ps[0] = rsc[0] + rsc[1] + rsc[2] + rsc[3];
        ps[1] = rsc[8] + rsc[9] + rsc[10] + rsc[11];
    }
}

__device__ __forceinline__ void lvl(const float* src, int sin, float* dstL,
                                    float* dstG, int sout, const float* kreg,
                                    float* rsc, float* ps) {
    float sm = 0.f, sq = 0.f;
    int n = sout * sout;
    for (int i = threadIdx.x; i < n; i += 256) {
        int oi = i / sout, oj = i - oi * sout;
        float acc = 0.f;
        #pragma unroll
        for (int u = 0; u < 3; ++u) {
            int r = 3 * oi - 1 + u;
            if ((unsigned)r >= (unsigned)sin) continue;
            #pragma unroll
            for (int v = 0; v < 3; ++v) {
                int cc = 3 * oj - 1 + v;
                if ((unsigned)cc >= (unsigned)sin) continue;
                acc += src[r * sin + cc] * kreg[u * 3 + v];
            }
        }
        dstG[i] = acc;
        if (dstL) dstL[i] = acc;
        float w = repw(oi, sout) * repw(oj, sout);
        sm += w * acc;
        sq += w * acc * acc;
    }
    red_store(sm, sq, rsc, ps);
}

__global__ __launch_bounds__(256) void pyramid_kernel(const float* __restrict__ d1,
                                                      float* __restrict__ d2,
                                                      float* __restrict__ d3,
                                                      float* __restrict__ d4,
                                                      float* __restrict__ d5,
                                                      float* __restrict__ d6,
                                                      const float* __restrict__ kd,
                                                      float* __restrict__ pstats) {
    __shared__ float buf2[3249];
    __shared__ float buf3[361];
    __shared__ float buf4[49];
    __shared__ float buf5[9];
    __shared__ float rsc[16];
    int bc = blockIdx.x;
    int c = bc & 31;
    float kreg[9];
    #pragma unroll
    for (int qq = 0; qq < 9; ++qq) kreg[qq] = kd[c * 9 + qq];
    float* ps = pstats + (size_t)bc * 12;
    const float* s1 = d1 + (size_t)bc * 29241;
    float sm = 0.f, sq = 0.f;
    for (int i = threadIdx.x; i < 29241; i += 256) {
        int oi = i / 171, oj = i - oi * 171;
        float w = repw(oi, 171) * repw(oj, 171);
        float v = s1[i];
        sm += w * v;
        sq += w * v * v;
    }
    red_store(sm, sq, rsc, ps + 0);
    lvl(s1, 171, buf2, d2 + (size_t)bc * 3249, 57, kreg, rsc, ps + 2);
    lvl(buf2, 57, buf3, d3 + (size_t)bc * 361, 19, kreg, rsc, ps + 4);
    lvl(buf3, 19, buf4, d4 + (size_t)bc * 49, 7, kreg, rsc, ps + 6);
    lvl(buf4, 7, buf5, d5 + (size_t)bc * 9, 3, kreg, rsc, ps + 8);
    lvl(buf5, 3, nullptr, d6 + bc, 1, kreg, rsc, ps + 10);
}

// Separate fin3 (proven shape), reading non-atomic pstats.
__global__ void fin3_kernel(const float* __restrict__ pstats, const float* __restrict__ kw,
                            const float* __restrict__ gw, const float* __restrict__ bw,
                            const float* __restrict__ kh, const float* __restrict__ gh,
                            const float* __restrict__ bh, float* __restrict__ lp) {
    int t = threadIdx.x;
    if (t >= 192) return;
    int l = t >> 5, c = t & 31;
    float sm = 0.f, sq = 0.f;
    #pragma unroll
    for (int b = 0; b < 4; ++b) {
        const float* ps = pstats + (size_t)(b * 32 + c) * 12 + 2 * l;
        sm += ps[0];
        sq += ps[1];
    }
    float mz = sm / NPIXF;
    float vz = sq / NPIXF - mz * mz;
    float kwc = kw[c];
    float aw = gw[c] * rsqrtf(kwc * kwc * vz + 1e-5f);
    float khc = kh[c];
    float ah = gh[c] * rsqrtf(khc * khc * vz + 1e-5f);
    float* o = lp + (size_t)(l * 32 + c) * 4;
    o[0] = kwc * aw;
    o[1] = bw[c] - kwc * mz * aw;
    o[2] = khc * ah;
    o[3] = bh[c] - khc * mz * ah;
}

// Final v2: each block owns one (b,c) plane slice -> lp coefficients AND
// the 24 source-column indices are loop-invariant per thread (hoisted).
// 2048 blocks x 16 iters, 4 px/thread, nontemporal f4 stores.
__global__ __launch_bounds__(256) void final_kernel(const float* __restrict__ d1,
                                                    const float* __restrict__ d2,
                                                    const float* __restrict__ d3,
                                                    const float* __restrict__ d4,
                                                    const float* __restrict__ d5,
                                                    const float* __restrict__ d6,
                                                    const float* __restrict__ lp,
                                                    float* __restrict__ out) {
    const float* ds[6] = {d1, d2, d3, d4, d5, d6};
    const int ss[6] = {171, 57, 19, 7, 3, 1};
    int bc = blockIdx.x >> 4;          // 0..127 = (b,c)
    int b = bc >> 5, c = bc & 31;
    int sub = blockIdx.x & 15;         // 32-row band within the plane
    int w4 = (threadIdx.x & 127) << 2;
    int tOff = threadIdx.x >> 7;       // which of the 2 rows in a 256-thread slab
    float ca0[6], ca1[6], ca2[6], ca3[6];
    int sw[6][4];
    const float* bases[6];
    #pragma unroll
    for (int l = 0; l < 6; ++l) {
        int s = ss[l];
        const float* a = lp + (size_t)(l * 32 + c) * 4;
        ca0[l] = a[0]; ca1[l] = a[1]; ca2[l] = a[2]; ca3[l] = a[3];
        #pragma unroll
        for (int k = 0; k < 4; ++k) sw[l][k] = ((w4 + k) * s) >> 9;
        bases[l] = ds[l] + (size_t)(b * 32 + c) * s * s;
    }
    size_t obase = (((size_t)(b * 64 + c)) << 18) + w4;
    #pragma unroll 1
    for (int it = 0; it < 16; ++it) {
        int h = sub * 32 + it * 2 + tOff;
        float accw[4] = {0.f, 0.f, 0.f, 0.f};
        float acch[4] = {0.f, 0.f, 0.f, 0.f};
        #pragma unroll
        for (int l = 0; l < 6; ++l) {
            int s = ss[l];
            int sh = (h * s) >> 9;
            const float* base = bases[l] + sh * s;
            float a0 = ca0[l], a1 = ca1[l], a2 = ca2[l], a3 = ca3[l];
            #pragma unroll
            for (int k = 0; k < 4; ++k) {
                float val = base[sw[l][k]];
                accw[k] += leaky(val * a0 + a1);
                acch[k] += leaky(val * a2 + a3);
            }
        }
        size_t o = obase + ((size_t)h << 9);
        f4 vw = {accw[0], accw[1], accw[2], accw[3]};
        f4 vh = {acch[0], acch[1], acch[2], acch[3]};
        __builtin_nontemporal_store(vw, (f4*)(out + o));
        __builtin_nontemporal_store(vh, (f4*)(out + o + (((size_t)32) << 18)));
    }
}

extern "C" void kernel_launch(void* const* d_in, const int* in_sizes, int n_in,
                              void* d_out, int out_size, void* d_ws, size_t ws_size,
                              hipStream_t stream) {
    const float* x     = (const float*)d_in[0];
    const float* w1    = (const float*)d_in[1];
    const float* b1    = (const float*)d_in[2];
    const float* w2    = (const float*)d_in[3];
    const float* b2    = (const float*)d_in[4];
    const float* bn1g  = (const float*)d_in[5];
    const float* bn1b  = (const float*)d_in[6];
    const float* w3    = (const float*)d_in[7];
    const float* b3    = (const float*)d_in[8];
    const float* bn2g  = (const float*)d_in[9];
    const float* bn2b  = (const float*)d_in[10];
    const float* kd    = (const float*)d_in[11];
    const float* kw    = (const float*)d_in[12];
    const float* bnwg  = (const float*)d_in[13];
    const float* bnwb  = (const float*)d_in[14];
    const float* kh    = (const float*)d_in[15];
    const float* bnhg  = (const float*)d_in[16];
    const float* bnhb  = (const float*)d_in[17];
    float* out = (float*)d_out;

    char* ws = (char*)d_ws;
    unsigned char* modeq = (unsigned char*)ws;             // 3,145,728 B
    float* pstats = (float*)(ws + 3145728);                // 128*12 f = 6,144 B
    float* p1 = (float*)(ws + 3151872);                    // 64 f
    float* p2 = p1 + 64;                                   // 64 f
    float* lp = p2 + 64;                                   // 768 f
    float* histf = (float*)(ws + 3155968);                 // 4913 f (pad to 20,480 B)
    unsigned* partial = (unsigned*)(ws + 3155968 + 20480); // 128*4913 u32 = 2,515,456 B
    float* d1 = (float*)(ws + 3176448 + 2515456);          // 3,742,848 f
    float* d2 = d1 + 3742848;                              // 415,872 f
    float* d3 = d2 + 415872;                               // 46,208 f
    float* d4 = d3 + 46208;                                // 6,272 f
    float* d5 = d4 + 6272;                                 // 1,152 f
    float* d6 = d5 + 1152;                                 // 128 f

    mode_kernel<<<dim3(2, 32, 12), 256, 0, stream>>>(x, modeq);
    hist_kernel<<<128, 256, 0, stream>>>(modeq, partial);
    redhist_kernel<<<20, 256, 0, stream>>>(partial, histf);
    solveB3_kernel<<<32, 256, 0, stream>>>(histf, w1, b1, w2, b2, bn1g, bn1b,
                                           w3, b3, bn2g, bn2b, p1, p2);
    d1_kernel<<<dim3(171, 4), 192, 0, stream>>>(modeq, w1, b1, w2, b2, w3, b3,
                                                p1, p2, kd, d1);
    pyramid_kernel<<<128, 256, 0, stream>>>(d1, d2, d3, d4, d5, d6, kd, pstats);
    fin3_kernel<<<1, 192, 0, stream>>>(pstats, kw, bnwg, bnwb, kh, bnhg, bnhb, lp);
    final_kernel<<<2048, 256, 0, stream>>>(d1, d2, d3, d4, d5, d6, lp, out);
}